// Round 4
// baseline (9870.254 us; speedup 1.0000x reference)
//
#include <hip/hip_runtime.h>
#include <cstdint>
#include <cstddef>

#define NB 32
#define NT 2048
#define ND 256
#define NH 256
#define NG 1024   // 4*H
#define ROWS 16   // bt-rows per block in zx_kernel

#define TPB 256            // 4 waves/CU, 1 wave/EU -> 512-VGPR unified budget
#define KL  76             // k-values with weights in LDS (19 uint2 rows = 152 KB)
#define NQ  90             // f16 packs per column in regs: (256-KL)/2

typedef _Float16 h2_t __attribute__((ext_vector_type(2)));

__device__ __forceinline__ float sigf(float x) {
    return 1.0f / (1.0f + __expf(-x));
}
__device__ __forceinline__ float tanh_fast(float x) {
    return 2.0f / (1.0f + __expf(-2.0f * x)) - 1.0f;
}

__device__ __forceinline__ h2_t as_h2(uint32_t u) {
    union { uint32_t u; h2_t h; } c; c.u = u; return c.h;
}
__device__ __forceinline__ uint32_t packf16(float a, float b) {
    union { uint32_t u; h2_t h; } c;
    c.h[0] = (_Float16)a; c.h[1] = (_Float16)b;
    return c.u;
}
__device__ __forceinline__ float dot2(uint32_t hpack, uint32_t wpack, float acc) {
    return __builtin_amdgcn_fdot2(as_h2(hpack), as_h2(wpack), acc, false);
}

// ---------------------------------------------------------------------------
// Phase 1: ZX[bt][j] = sum_k X[bt][k] * Wi[k][j] + bias[j]
__global__ __launch_bounds__(256) void zx_kernel(const float* __restrict__ X,
                                                 const float* __restrict__ Wi,
                                                 const float* __restrict__ bias,
                                                 float* __restrict__ ZX) {
    __shared__ float xs[ROWS][ND];
    const int tid = threadIdx.x;
    const size_t row0 = (size_t)blockIdx.x * ROWS;

    const float4* Xv = (const float4*)(X + row0 * ND);
    float4* xsv = (float4*)(&xs[0][0]);
#pragma unroll
    for (int i = 0; i < (ROWS * ND / 4) / 256; ++i)
        xsv[tid + i * 256] = Xv[tid + i * 256];
    __syncthreads();

    const int j0 = tid * 4;
    const float4 bv = *(const float4*)(bias + j0);
    float acc[ROWS][4];
#pragma unroll
    for (int r = 0; r < ROWS; ++r) {
        acc[r][0] = bv.x; acc[r][1] = bv.y; acc[r][2] = bv.z; acc[r][3] = bv.w;
    }

    for (int k = 0; k < ND; ++k) {
        const float4 w = *(const float4*)(Wi + (size_t)k * NG + j0);
#pragma unroll
        for (int r = 0; r < ROWS; ++r) {
            const float x = xs[r][k];
            acc[r][0] = fmaf(x, w.x, acc[r][0]);
            acc[r][1] = fmaf(x, w.y, acc[r][1]);
            acc[r][2] = fmaf(x, w.z, acc[r][2]);
            acc[r][3] = fmaf(x, w.w, acc[r][3]);
        }
    }

#pragma unroll
    for (int r = 0; r < ROWS; ++r) {
        float4 o;
        o.x = acc[r][0]; o.y = acc[r][1]; o.z = acc[r][2]; o.w = acc[r][3];
        *(float4*)(ZX + (row0 + r) * NG + j0) = o;
    }
}

// ---------------------------------------------------------------------------
// Phase 2: persistent-weight recurrence. One block per batch, 256 threads.
// Thread tid owns gate columns {tid, tid+256, tid+512, tid+768} = (i,f,g,o)
// of hidden unit tid -> gate math is thread-local, ONE barrier per step.
// Wh as packed f16: k=0..KL-1 in LDS (152 KB), k=KL..255 in 360 VGPRs/thread.
// 4 waves/CU = 1 wave/EU; waves_per_eu(1,1) unlocks the full 512-reg budget.
__global__ __launch_bounds__(TPB)
__attribute__((amdgpu_waves_per_eu(1, 1)))
void rec_pers(
    const float* __restrict__ ZX,
    const float* __restrict__ Wh,
    const int* __restrict__ lengths,
    float* __restrict__ out)
{
    __shared__ uint2 lw[KL / 4][NG];              // 152 KB: row r = k 4r..4r+3
    __shared__ __align__(16) _Float16 hs_h[NH];   // 512 B hidden state, f16

    const int b   = blockIdx.x;
    const int tid = threadIdx.x;

    // ---- one-time weight staging (coalesced over j at fixed k) ----
    for (int r = 0; r < KL / 4; ++r) {
        const int k = r * 4;
#pragma unroll
        for (int cidx = 0; cidx < 4; ++cidx) {
            const int j = tid + cidx * 256;
            uint2 p;
            p.x = packf16(Wh[(size_t)(k + 0) * NG + j], Wh[(size_t)(k + 1) * NG + j]);
            p.y = packf16(Wh[(size_t)(k + 2) * NG + j], Wh[(size_t)(k + 3) * NG + j]);
            lw[r][j] = p;
        }
    }

    uint32_t w0[NQ], w1[NQ], w2[NQ], w3[NQ];
#pragma unroll
    for (int q = 0; q < NQ; ++q) {
        const int k = KL + 2 * q;
        w0[q] = packf16(Wh[(size_t)k * NG + tid +   0], Wh[(size_t)(k + 1) * NG + tid +   0]);
        w1[q] = packf16(Wh[(size_t)k * NG + tid + 256], Wh[(size_t)(k + 1) * NG + tid + 256]);
        w2[q] = packf16(Wh[(size_t)k * NG + tid + 512], Wh[(size_t)(k + 1) * NG + tid + 512]);
        w3[q] = packf16(Wh[(size_t)k * NG + tid + 768], Wh[(size_t)(k + 1) * NG + tid + 768]);
    }

    hs_h[tid] = (_Float16)0.0f;
    float c = 0.0f;
    float hlast = 0.0f;
    __syncthreads();

    const int len   = lengths[b];
    const int steps = (len < 1) ? 1 : len;    // idx = max(0, len-1) -> idx+1 steps

    for (int t = 0; t < steps; ++t) {
        // issue early; consumed only after the dot phase (hides L3/HBM latency)
        const size_t zb = ((size_t)b * NT + t) * NG + tid;
        const float zi = ZX[zb];
        const float zf = ZX[zb + 256];
        const float zg = ZX[zb + 512];
        const float zo = ZX[zb + 768];

        float ai = 0.0f, af = 0.0f, ag = 0.0f, ao = 0.0f;   // .x-lane accums
        float bi = 0.0f, bf = 0.0f, bg = 0.0f, bo = 0.0f;   // .y-lane accums

        // k = 0..KL-1: weights from LDS
#pragma unroll
        for (int r = 0; r < KL / 4; ++r) {
            const uint2 ha = *(const uint2*)(hs_h + 4 * r);   // broadcast
            const uint2 pi = lw[r][tid];
            const uint2 pf = lw[r][tid + 256];
            const uint2 pg = lw[r][tid + 512];
            const uint2 po = lw[r][tid + 768];
            ai = dot2(ha.x, pi.x, ai); bi = dot2(ha.y, pi.y, bi);
            af = dot2(ha.x, pf.x, af); bf = dot2(ha.y, pf.y, bf);
            ag = dot2(ha.x, pg.x, ag); bg = dot2(ha.y, pg.y, bg);
            ao = dot2(ha.x, po.x, ao); bo = dot2(ha.y, po.y, bo);
        }

        // k = KL..255: register-resident weights
#pragma unroll
        for (int q = 0; q < NQ; q += 2) {
            const uint2 hu = *(const uint2*)(hs_h + KL + 2 * q);  // broadcast
            ai = dot2(hu.x, w0[q], ai); bi = dot2(hu.y, w0[q + 1], bi);
            af = dot2(hu.x, w1[q], af); bf = dot2(hu.y, w1[q + 1], bf);
            ag = dot2(hu.x, w2[q], ag); bg = dot2(hu.y, w2[q + 1], bg);
            ao = dot2(hu.x, w3[q], ao); bo = dot2(hu.y, w3[q + 1], bo);
        }

        const float iv = zi + ai + bi;
        const float fv = zf + af + bf;
        const float gv = zg + ag + bg;
        const float ov = zo + ao + bo;

        c = sigf(fv) * c + sigf(iv) * tanh_fast(gv);
        hlast = sigf(ov) * tanh_fast(c);
        __syncthreads();                       // all reads of old hs_h done
        hs_h[tid] = (_Float16)hlast;
        __syncthreads();                       // new h visible
    }

    out[(size_t)b * NH + tid] = hlast;
}

// ---------------------------------------------------------------------------
// Fallback recurrence (streams weights; used only if ws can't hold ZX)
__global__ __launch_bounds__(512) void rec_fallback(
    const float* __restrict__ X,
    const float* __restrict__ Wi,
    const float* __restrict__ Wh,
    const float* __restrict__ bias,
    const int* __restrict__ lengths,
    float* __restrict__ out)
{
    __shared__ float hs[NH];
    __shared__ float zs[NG];
    __shared__ float xs[ND];

    const int b   = blockIdx.x;
    const int tid = threadIdx.x;
    const int c0  = tid * 2;

    const int len   = lengths[b];
    const int steps = (len < 1) ? 1 : len;

    float c_state = 0.0f;
    if (tid < NH) hs[tid] = 0.0f;
    const float b0 = bias[c0], b1 = bias[c0 + 1];
    __syncthreads();

    for (int t = 0; t < steps; ++t) {
        float a0 = b0, a1 = b1;
        if (tid < ND) xs[tid] = X[((size_t)b * NT + t) * ND + tid];
        __syncthreads();
#pragma unroll 2
        for (int k = 0; k < ND; k += 4) {
            const float4 xv = *(const float4*)(xs + k);
            const float2 w0 = *(const float2*)(Wi + (size_t)(k + 0) * NG + c0);
            const float2 w1 = *(const float2*)(Wi + (size_t)(k + 1) * NG + c0);
            const float2 w2 = *(const float2*)(Wi + (size_t)(k + 2) * NG + c0);
            const float2 w3 = *(const float2*)(Wi + (size_t)(k + 3) * NG + c0);
            a0 = fmaf(xv.x, w0.x, a0); a1 = fmaf(xv.x, w0.y, a1);
            a0 = fmaf(xv.y, w1.x, a0); a1 = fmaf(xv.y, w1.y, a1);
            a0 = fmaf(xv.z, w2.x, a0); a1 = fmaf(xv.z, w2.y, a1);
            a0 = fmaf(xv.w, w3.x, a0); a1 = fmaf(xv.w, w3.y, a1);
        }
#pragma unroll 2
        for (int k = 0; k < NH; k += 4) {
            const float4 hv = *(const float4*)(hs + k);
            const float2 w0 = *(const float2*)(Wh + (size_t)(k + 0) * NG + c0);
            const float2 w1 = *(const float2*)(Wh + (size_t)(k + 1) * NG + c0);
            const float2 w2 = *(const float2*)(Wh + (size_t)(k + 2) * NG + c0);
            const float2 w3 = *(const float2*)(Wh + (size_t)(k + 3) * NG + c0);
            a0 = fmaf(hv.x, w0.x, a0); a1 = fmaf(hv.x, w0.y, a1);
            a0 = fmaf(hv.y, w1.x, a0); a1 = fmaf(hv.y, w1.y, a1);
            a0 = fmaf(hv.z, w2.x, a0); a1 = fmaf(hv.z, w2.y, a1);
            a0 = fmaf(hv.w, w3.x, a0); a1 = fmaf(hv.w, w3.y, a1);
        }

        float2 zo2; zo2.x = a0; zo2.y = a1;
        *(float2*)(zs + c0) = zo2;
        __syncthreads();

        if (tid < NH) {
            const float iv = zs[tid];
            const float fv = zs[NH + tid];
            const float gv = zs[2 * NH + tid];
            const float ov = zs[3 * NH + tid];
            c_state = sigf(fv) * c_state + sigf(iv) * tanh_fast(gv);
            hs[tid] = sigf(ov) * tanh_fast(c_state);
        }
        __syncthreads();
    }

    if (tid < NH) out[(size_t)b * NH + tid] = hs[tid];
}

extern "C" void kernel_launch(void* const* d_in, const int* in_sizes, int n_in,
                              void* d_out, int out_size, void* d_ws, size_t ws_size,
                              hipStream_t stream) {
    const float* X       = (const float*)d_in[0];
    const int*   lengths = (const int*)d_in[1];
    const float* Wi      = (const float*)d_in[2];
    const float* Wh      = (const float*)d_in[3];
    const float* bias    = (const float*)d_in[4];
    float* out = (float*)d_out;

    const size_t zx_bytes = (size_t)NB * NT * NG * sizeof(float);  // 256 MB
    float* ZX = (float*)d_ws;

    if (ws_size >= zx_bytes) {
        zx_kernel<<<dim3((NB * NT) / ROWS), dim3(256), 0, stream>>>(X, Wi, bias, ZX);
        rec_pers<<<dim3(NB), dim3(TPB), 0, stream>>>(ZX, Wh, lengths, out);
    } else {
        rec_fallback<<<dim3(NB), dim3(512), 0, stream>>>(X, Wi, Wh, bias, lengths, out);
    }
}